// Round 11
// baseline (3101.921 us; speedup 1.0000x reference)
//
#include <hip/hip_runtime.h>
#include <math.h>

#define B_SZ 4096
#define D_SZ 1024
#define H_SZ 1024
#define T_SZ 50

typedef _Float16 f16;
typedef __attribute__((ext_vector_type(8))) _Float16 f16x8;
typedef __attribute__((ext_vector_type(4))) _Float16 f16x4;
typedef __attribute__((ext_vector_type(4))) float f32x4;
typedef __attribute__((ext_vector_type(16))) float f32x16;
typedef __attribute__((ext_vector_type(4))) float f4;

// fast activations: 1 v_exp + 1 v_rcp each; error ~1e-6, far below fp16 noise
__device__ __forceinline__ float fast_sigmoid(float x) {
    return 1.0f / (1.0f + __expf(-x));
}
__device__ __forceinline__ float fast_tanh(float x) {
    return 1.0f - 2.0f / (__expf(2.0f * x) + 1.0f);
}

// async global->LDS, 16 bytes per lane
__device__ __forceinline__ void gl_lds16(const void* g, void* l) {
    __builtin_amdgcn_global_load_lds(
        (const __attribute__((address_space(1))) unsigned int*)g,
        (__attribute__((address_space(3))) unsigned int*)l, 16, 0, 0);
}

// ---------------------------------------------------------------------------
// fp32 -> fp16 conversion (4 elems/thread; n divisible by 4)
__global__ __launch_bounds__(256) void conv_kernel(
        const float* __restrict__ s, f16* __restrict__ d, int n) {
    int i = (blockIdx.x * 256 + threadIdx.x) * 4;
    if (i < n) {
        f4 v = *(const f4*)&s[i];
        f16x4 o = {(f16)v[0], (f16)v[1], (f16)v[2], (f16)v[3]};
        *(f16x4*)&d[i] = o;
    }
}

// ---------------------------------------------------------------------------
// h0 = tanh(ev @ w_init^T + b_init) via fp16 MFMA (16x16x32 path, unchanged).
__global__ __launch_bounds__(256, 2) void h0_kernel(
        const f16* __restrict__ ev, const f16* __restrict__ wi,
        const float* __restrict__ b_init, f16* __restrict__ hh) {
    __shared__ __align__(16) f16 lds[6144];  // A 128x32 @0, B 64x32 @4096
    const int tid = threadIdx.x;
    const int lane = tid & 63, wave = tid >> 6;
    const int b0 = blockIdx.y * 128, j0 = blockIdx.x * 64;
    const int wm = wave >> 1, wn = wave & 1;
    const int lrow = lane & 15, quad = lane >> 4;

    const f16* gsrc[3];
    int lbase[3];
    {
        const int row16 = lane >> 2, part = lane & 3;
#pragma unroll
        for (int i = 0; i < 3; ++i) {
            int c = wave + 4 * i;
            if (c < 8) {
                gsrc[i] = ev + (size_t)(b0 + c * 16 + row16) * D_SZ + part * 8;
                lbase[i] = c * 512;
            } else {
                int cc = c - 8;
                gsrc[i] = wi + (size_t)(j0 + cc * 16 + row16) * D_SZ + part * 8;
                lbase[i] = 4096 + cc * 512;
            }
        }
    }

    int offA[4], offB[2];
#pragma unroll
    for (int mi = 0; mi < 4; ++mi)
        offA[mi] = (wm * 64 + mi * 16 + lrow) * 32 + quad * 8;
#pragma unroll
    for (int ni = 0; ni < 2; ++ni)
        offB[ni] = 4096 + (wn * 32 + ni * 16 + lrow) * 32 + quad * 8;

    f32x4 acc[4][2] = {};

    for (int k0 = 0; k0 < D_SZ; k0 += 32) {
        __syncthreads();
#pragma unroll
        for (int i = 0; i < 3; ++i)
            gl_lds16(gsrc[i] + k0, &lds[lbase[i]] + lane * 8);
        __syncthreads();
        f16x8 aa[4], bb[2];
#pragma unroll
        for (int mi = 0; mi < 4; ++mi) aa[mi] = *(const f16x8*)&lds[offA[mi]];
#pragma unroll
        for (int ni = 0; ni < 2; ++ni) bb[ni] = *(const f16x8*)&lds[offB[ni]];
#pragma unroll
        for (int mi = 0; mi < 4; ++mi)
#pragma unroll
            for (int ni = 0; ni < 2; ++ni)
                acc[mi][ni] = __builtin_amdgcn_mfma_f32_16x16x32_f16(
                    aa[mi], bb[ni], acc[mi][ni], 0, 0, 0);
    }

#pragma unroll
    for (int ni = 0; ni < 2; ++ni) {
        const int j = j0 + wn * 32 + ni * 16 + lrow;
        const float bj = b_init[j];
#pragma unroll
        for (int mi = 0; mi < 4; ++mi)
#pragma unroll
            for (int reg = 0; reg < 4; ++reg) {
                const int b = b0 + wm * 64 + mi * 16 + quad * 4 + reg;
                hh[(size_t)b * H_SZ + j] = (f16)tanhf(acc[mi][ni][reg] + bj);
            }
    }
}

// ---------------------------------------------------------------------------
// One GRU step: gh = h @ w_hh^T via 32x32x16 fp16 MFMA, double-buffered
// BK=64 windows with in-register cross-slice pipelining.
// Grid (16 jb, 16 mb) = 256 blocks = 1/CU (traffic-optimal, R10).
// Block 256(M) x 64(j) x 3g; 8 waves (4 wm x 2 wn); wave 64M x (32j x 3g).
// acc: 2 mfrag x 3 gate f32x16 = 96 VGPR; __launch_bounds__(512,1) lifts
// R10's 128-VGPR cap (which pinned VGPR_Count==128 -> serialized/spilled).
// Per window: 20 ds_read_b128 (both slices up-front -> MFMA(s0) overlaps
// ds_read(s1) within-wave) + 24 long MFMAs; 16 barriers/step (was 32).
// LDS: 2 buffers x (A[256][64-as-2x32] + B[192][64]) = 112 KB.
__global__ __launch_bounds__(512, 1) void step_kernel(
        const f16* __restrict__ hh, const f16* __restrict__ w,
        const float* __restrict__ b_hh, const float* __restrict__ w_ih,
        const float* __restrict__ b_ih, const float* __restrict__ w_out,
        const float* __restrict__ teach, f16* __restrict__ nhh,
        float* __restrict__ out, int t) {
    __shared__ __align__(16) f16 lds[57344];  // 2 x 28672 (A 2x8192 + B 2x6144)
    const int tid = threadIdx.x;
    const int lane = tid & 63, wave = tid >> 6;  // 0..7
    const int wm = wave & 3, wn = wave >> 2;     // 4 x 2
    const int mb0 = blockIdx.y * 256;
    const int j0 = blockIdx.x * 64;
    const int l31 = lane & 31, half = lane >> 5;

    // staging (per BK=32 slice): 28 chunks (A 16, B 12), 16 rows x 32 k each;
    // wave takes chunks wave, wave+8, wave+16, wave+24(<28).
    const f16* gsrc[4];
    int lsub[4];   // offset within slice-sub-buffer region
    int isA[4];
    {
        const int r4 = lane >> 2, c4 = lane & 3;
#pragma unroll
        for (int i = 0; i < 4; ++i) {
            int c = wave + 8 * i;
            if (c < 16) {
                gsrc[i] = hh + (size_t)(mb0 + c * 16 + r4) * H_SZ + c4 * 8;
                lsub[i] = c * 512 + lane * 8;
                isA[i] = 1;
            } else if (c < 28) {
                int cb = c - 16;
                int gr = cb * 16 + r4;  // 0..191 = gate*64 + jj
                gsrc[i] = w + (size_t)((gr >> 6) * H_SZ + j0 + (gr & 63)) * H_SZ +
                          c4 * 8;
                lsub[i] = cb * 512 + lane * 8;
                isA[i] = 0;
            } else {
                gsrc[i] = nullptr;
                lsub[i] = 0;
                isA[i] = -1;
            }
        }
    }

    // ds_read offsets within a buffer (f16 units), 32x32x16 operand layout:
    // lane reads row (lane&31), k = half*8 .. +7, per kh half of the 32-slice.
    int offA[2][2], offB[3][2];  // [mfrag][kh], [gate][kh]
#pragma unroll
    for (int mf = 0; mf < 2; ++mf)
#pragma unroll
        for (int kh = 0; kh < 2; ++kh)
            offA[mf][kh] = (wm * 64 + mf * 32 + l31) * 32 + kh * 16 + half * 8;
#pragma unroll
    for (int g = 0; g < 3; ++g)
#pragma unroll
        for (int kh = 0; kh < 2; ++kh)
            offB[g][kh] = 16384 + (g * 64 + wn * 32 + l31) * 32 + kh * 16 + half * 8;

    f32x16 acc[2][3] = {};  // [mfrag][gate]

    auto issue = [&](int kelem, int bufbase, int s) {
#pragma unroll
        for (int i = 0; i < 4; ++i) {
            if (isA[i] == 1)
                gl_lds16(gsrc[i] + kelem, &lds[bufbase + s * 8192 + lsub[i]]);
            else if (isA[i] == 0)
                gl_lds16(gsrc[i] + kelem, &lds[bufbase + 16384 + s * 6144 + lsub[i]]);
        }
    };

    issue(0, 0, 0);
    issue(32, 0, 1);
    __syncthreads();  // window 0 landed
    for (int wnd = 0; wnd < 16; ++wnd) {
        const int buf = (wnd & 1) * 28672;
        const int nbuf = ((wnd + 1) & 1) * 28672;
        if (wnd + 1 < 16) {
            issue((wnd + 1) * 64, nbuf, 0);
            issue((wnd + 1) * 64 + 32, nbuf, 1);
        }
        // read BOTH slices' fragments; MFMA(s0) overlaps ds_read(s1)
        f16x8 aa[2][2][2], bb[2][3][2];  // [s][mf/g][kh]
#pragma unroll
        for (int s = 0; s < 2; ++s) {
#pragma unroll
            for (int mf = 0; mf < 2; ++mf)
#pragma unroll
                for (int kh = 0; kh < 2; ++kh)
                    aa[s][mf][kh] = *(const f16x8*)&lds[buf + s * 8192 + offA[mf][kh]];
#pragma unroll
            for (int g = 0; g < 3; ++g)
#pragma unroll
                for (int kh = 0; kh < 2; ++kh)
                    bb[s][g][kh] = *(const f16x8*)&lds[buf + s * 6144 + offB[g][kh]];
        }
#pragma unroll
        for (int s = 0; s < 2; ++s)
#pragma unroll
            for (int kh = 0; kh < 2; ++kh)
#pragma unroll
                for (int g = 0; g < 3; ++g)
#pragma unroll
                    for (int mf = 0; mf < 2; ++mf)
                        acc[mf][g] = __builtin_amdgcn_mfma_f32_32x32x16_f16(
                            aa[s][mf][kh], bb[s][g][kh], acc[mf][g], 0, 0, 0);
        __syncthreads();  // my reads done; next window's loads landed
    }

    // -------- fused epilogue (32x32 C/D layout): gates, h_next, deltas ----
    // col(j) = lane&31 (one j per thread); row = (reg&3)+8*(reg>>2)+4*half.
    const int j = j0 + wn * 32 + l31;
    const float wr0 = w_ih[(0 * H_SZ + j) * 2 + 0];
    const float wr1 = w_ih[(0 * H_SZ + j) * 2 + 1];
    const float wz0 = w_ih[(1 * H_SZ + j) * 2 + 0];
    const float wz1 = w_ih[(1 * H_SZ + j) * 2 + 1];
    const float wn0 = w_ih[(2 * H_SZ + j) * 2 + 0];
    const float wn1 = w_ih[(2 * H_SZ + j) * 2 + 1];
    const float br = b_ih[0 * H_SZ + j] + b_hh[0 * H_SZ + j];
    const float bz = b_ih[1 * H_SZ + j] + b_hh[1 * H_SZ + j];
    const float bn = b_ih[2 * H_SZ + j];
    const float hbn = b_hh[2 * H_SZ + j];
    const float wo0 = w_out[j], wo1 = w_out[H_SZ + j];

#pragma unroll
    for (int mf = 0; mf < 2; ++mf) {
#pragma unroll
        for (int reg = 0; reg < 16; ++reg) {
            const int row = (reg & 3) + 8 * (reg >> 2) + 4 * half;
            const int b = mb0 + wm * 64 + mf * 32 + row;
            float p0 = 0.f, p1 = 0.f;
            if (t > 0) {
                p0 = teach[b * (T_SZ * 2) + (t - 1) * 2 + 0];
                p1 = teach[b * (T_SZ * 2) + (t - 1) * 2 + 1];
            }
            const float hr = acc[mf][0][reg];
            const float hz = acc[mf][1][reg];
            const float hn_ = acc[mf][2][reg] + hbn;
            const float xr = wr0 * p0 + wr1 * p1 + br;
            const float xz = wz0 * p0 + wz1 * p1 + bz;
            const float xn = wn0 * p0 + wn1 * p1 + bn;
            const float r = fast_sigmoid(xr + hr);
            const float z = fast_sigmoid(xz + hz);
            const float n = fast_tanh(xn + r * hn_);
            const size_t idx = (size_t)b * H_SZ + j;
            const float hold = (float)hh[idx];
            const float hnew = (1.0f - z) * n + z * hold;
            nhh[idx] = (f16)hnew;
            // delta partials: reduce over the 32 j-lanes of this half
            float s0 = hnew * wo0;
            float s1 = hnew * wo1;
#pragma unroll
            for (int m = 1; m < 32; m <<= 1) {
                s0 += __shfl_xor(s0, m);
                s1 += __shfl_xor(s1, m);
            }
            if (l31 == 0) {
                atomicAdd(&out[b * (T_SZ * 2) + t * 2 + 0], s0);
                atomicAdd(&out[b * (T_SZ * 2) + t * 2 + 1], s1);
            }
        }
    }
}

// ---------------------------------------------------------------------------
// pred_deltas += b_out; pred_pos = cumsum
__global__ __launch_bounds__(256) void final_kernel(
        float* __restrict__ out, float* __restrict__ pos,
        const float* __restrict__ b_out) {
    int idx = blockIdx.x * 256 + threadIdx.x;  // b*2 + c
    if (idx >= B_SZ * 2) return;
    int b = idx >> 1, c = idx & 1;
    float bc = b_out[c];
    float acc = 0.0f;
    for (int t = 0; t < T_SZ; ++t) {
        float d = out[b * (T_SZ * 2) + t * 2 + c] + bc;
        out[b * (T_SZ * 2) + t * 2 + c] = d;
        acc += d;
        pos[b * (T_SZ * 2) + t * 2 + c] = acc;
    }
}

// ---------------------------------------------------------------------------
extern "C" void kernel_launch(void* const* d_in, const int* in_sizes, int n_in,
                              void* d_out, int out_size, void* d_ws, size_t ws_size,
                              hipStream_t stream) {
    const float* ev     = (const float*)d_in[0];
    const float* teach  = (const float*)d_in[1];
    const float* w_init = (const float*)d_in[2];
    const float* b_init = (const float*)d_in[3];
    const float* w_ih   = (const float*)d_in[4];
    const float* w_hh   = (const float*)d_in[5];
    const float* b_ih   = (const float*)d_in[6];
    const float* b_hh   = (const float*)d_in[7];
    const float* w_out  = (const float*)d_in[8];
    const float* b_out  = (const float*)d_in[9];

    float* out = (float*)d_out;                  // pred_deltas (B,T,2)
    float* pos = out + (size_t)B_SZ * T_SZ * 2;  // pred_pos    (B,T,2)

    // ws layout (f16 units): hA (4M), hB (4M), w_hh (3M), w_init (1M).
    // ev_f16 (4M) aliases hB (consumed by h0 before hB is first written).
    f16* ws = (f16*)d_ws;
    f16* hA    = ws;
    f16* hB    = hA + (size_t)B_SZ * H_SZ;
    f16* whh   = hB + (size_t)B_SZ * H_SZ;
    f16* winit = whh + (size_t)3 * H_SZ * H_SZ;
    f16* evf   = hB;  // alias

    hipMemsetAsync(out, 0, (size_t)B_SZ * T_SZ * 2 * sizeof(float), stream);

    conv_kernel<<<(3 * H_SZ * H_SZ) / 1024, 256, 0, stream>>>(w_hh, whh, 3 * H_SZ * H_SZ);
    conv_kernel<<<(H_SZ * D_SZ) / 1024, 256, 0, stream>>>(w_init, winit, H_SZ * D_SZ);
    conv_kernel<<<(B_SZ * D_SZ) / 1024, 256, 0, stream>>>(ev, evf, B_SZ * D_SZ);

    dim3 g0(H_SZ / 64, B_SZ / 128);  // (16, 32)
    h0_kernel<<<g0, 256, 0, stream>>>(evf, winit, b_init, hA);

    dim3 gs(16, 16);  // 256 blocks = 1/CU, 512 threads
    f16 *hc = hA, *hn = hB;
    for (int t = 0; t < T_SZ; ++t) {
        step_kernel<<<gs, 512, 0, stream>>>(hc, whh, b_hh, w_ih, b_ih, w_out,
                                            teach, hn, out, t);
        f16* tmp = hc; hc = hn; hn = tmp;
    }
    final_kernel<<<(B_SZ * 2 + 255) / 256, 256, 0, stream>>>(out, pos, b_out);
}